// Round 1
// baseline (678.487 us; speedup 1.0000x reference)
//
#include <hip/hip_runtime.h>
#include <hip/hip_bf16.h>
#include <stdint.h>

typedef unsigned short u16;
typedef __attribute__((ext_vector_type(8))) short   s16x8;
typedef __attribute__((ext_vector_type(8))) __bf16  bf16x8;
typedef __attribute__((ext_vector_type(4))) float   f32x4;

#define B_DIM 16
#define N_SEQ 2048
#define D_DIM 256
#define A_DIM 256
#define M_TOT (B_DIM * N_SEQ)   // 32768

static __device__ __forceinline__ u16 f2bf(float f) {
  union { float f; uint32_t u; } v; v.f = f;
  uint32_t u = v.u;
  return (u16)((u + 0x7FFFu + ((u >> 16) & 1u)) >> 16);   // RNE
}
static __device__ __forceinline__ float bf2f(u16 h) {
  union { uint32_t u; float f; } v; v.u = ((uint32_t)h) << 16;
  return v.f;
}

static __device__ __forceinline__ f32x4 MFMA(s16x8 a, s16x8 b, f32x4 c) {
  return __builtin_amdgcn_mfma_f32_16x16x32_bf16(
      __builtin_bit_cast(bf16x8, a), __builtin_bit_cast(bf16x8, b), c, 0, 0, 0);
}

// ---------------------------------------------------------------------------
// Projection: C = x @ [W1|W2|W3] + bias, written as split-bf16 (hi/lo) arrays.
// Q,K: row-major [B*N][A].  V: transposed [B][A][N] for PV fragment reads.
// Split-bf16 GEMM: acc += xh*wh + xh*wl + xl*wh  (~fp32 accuracy).
// ---------------------------------------------------------------------------
__global__ __launch_bounds__(256) void proj_kernel(
    const float* __restrict__ x,
    const float* __restrict__ W1, const float* __restrict__ b1,
    const float* __restrict__ W2, const float* __restrict__ b2,
    const float* __restrict__ W3, const float* __restrict__ b3,
    u16* __restrict__ Qh, u16* __restrict__ Ql,
    u16* __restrict__ Kh, u16* __restrict__ Kl,
    u16* __restrict__ Vth, u16* __restrict__ Vtl)
{
  // rows padded to 40 u16 (80 B, 16B-aligned, 20-bank stride -> 2-way = free)
  __shared__ u16 xh[64][40], xl[64][40];
  __shared__ u16 wh[64][40], wl[64][40];   // transposed: [col][k]

  const int bid = blockIdx.x;
  const int mt  = bid / 12;
  const int nt  = bid % 12;
  const int m0  = mt * 64;
  const int which = nt >> 2;            // 0=Q 1=K 2=V
  const int n0    = (nt & 3) * 64;
  const float* Wm   = (which == 0) ? W1 : (which == 1) ? W2 : W3;
  const float* bias = (which == 0) ? b1 : (which == 1) ? b2 : b3;

  const int t  = threadIdx.x;
  const int wv = t >> 6;
  const int ln = t & 63;
  const int lg = ln >> 4;               // 0..3
  const int lm = ln & 15;

  f32x4 acc[4] = {};

  for (int k0 = 0; k0 < D_DIM; k0 += 32) {
    __syncthreads();
    { // x tile 64 x 32, split hi/lo
      const int r = t >> 2, c = (t & 3) * 8;
      const float* src = x + (size_t)(m0 + r) * D_DIM + k0 + c;
      float4 v0 = *(const float4*)(src);
      float4 v1 = *(const float4*)(src + 4);
      float vv[8] = {v0.x, v0.y, v0.z, v0.w, v1.x, v1.y, v1.z, v1.w};
#pragma unroll
      for (int j = 0; j < 8; ++j) {
        u16 h = f2bf(vv[j]);
        xh[r][c + j] = h;
        xl[r][c + j] = f2bf(vv[j] - bf2f(h));
      }
    }
    { // W tile 32 x 64, transposed + split
      const int r = t >> 3, c = (t & 7) * 8;
      const float* src = Wm + (size_t)(k0 + r) * A_DIM + n0 + c;
      float4 v0 = *(const float4*)(src);
      float4 v1 = *(const float4*)(src + 4);
      float vv[8] = {v0.x, v0.y, v0.z, v0.w, v1.x, v1.y, v1.z, v1.w};
#pragma unroll
      for (int j = 0; j < 8; ++j) {
        u16 h = f2bf(vv[j]);
        wh[c + j][r] = h;
        wl[c + j][r] = f2bf(vv[j] - bf2f(h));
      }
    }
    __syncthreads();

    const int arow = wv * 16 + lm;
    s16x8 ah = *(const s16x8*)&xh[arow][lg * 8];
    s16x8 al = *(const s16x8*)&xl[arow][lg * 8];
#pragma unroll
    for (int tt = 0; tt < 4; ++tt) {
      s16x8 bh = *(const s16x8*)&wh[tt * 16 + lm][lg * 8];
      s16x8 bl = *(const s16x8*)&wl[tt * 16 + lm][lg * 8];
      acc[tt] = MFMA(ah, bh, acc[tt]);
      acc[tt] = MFMA(ah, bl, acc[tt]);
      acc[tt] = MFMA(al, bh, acc[tt]);
    }
  }

  // write out (C/D layout: col = lane&15, row = (lane>>4)*4 + reg)
#pragma unroll
  for (int tt = 0; tt < 4; ++tt) {
#pragma unroll
    for (int r = 0; r < 4; ++r) {
      const int mloc = wv * 16 + lg * 4 + r;
      const int aloc = tt * 16 + lm;
      const int m = m0 + mloc;
      const int a = n0 + aloc;
      float val = acc[tt][r] + bias[a];
      u16 h  = f2bf(val);
      u16 lo = f2bf(val - bf2f(h));
      if (which == 0) {
        size_t idx = (size_t)m * A_DIM + a;
        Qh[idx] = h; Ql[idx] = lo;
      } else if (which == 1) {
        size_t idx = (size_t)m * A_DIM + a;
        Kh[idx] = h; Kl[idx] = lo;
      } else {
        const int bb = m >> 11;       // / N_SEQ
        const int nn = m & (N_SEQ - 1);
        size_t idx = (size_t)bb * (A_DIM * N_SEQ) + (size_t)a * N_SEQ + nn;
        Vth[idx] = h; Vtl[idx] = lo;
      }
    }
  }
}

// ---------------------------------------------------------------------------
// Flash attention + query-sum. Block = 4 waves x 16 queries (64 q / block),
// KV tiles of 32 keys staged in LDS (XOR bank-swizzled), online softmax,
// atomicAdd of per-wave column sums into out[b][a].
// ---------------------------------------------------------------------------
#define QB 64
#define KB 32

__global__ __launch_bounds__(256) void attn_kernel(
    const u16* __restrict__ Qh, const u16* __restrict__ Ql,
    const u16* __restrict__ Kh, const u16* __restrict__ Kl,
    const u16* __restrict__ Vth, const u16* __restrict__ Vtl,
    float* __restrict__ out)
{
  extern __shared__ u16 smem[];
  u16* KhL = smem;            // [32][256] swizzled (8192 u16)
  u16* KlL = smem + 8192;
  u16* VhL = smem + 16384;    // [256][32] swizzled (8192 u16)
  u16* VlL = smem + 24576;
  u16* PL  = smem + 32768;    // [4 waves][16][40] (2560 u16)

  const int bb = blockIdx.x >> 5;
  const int qt = blockIdx.x & 31;
  const int q0 = qt * QB;
  const int t  = threadIdx.x;
  const int wv = t >> 6;
  const int ln = t & 63;
  const int lg = ln >> 4;
  const int lm = ln & 15;

  const u16* Kh_g = Kh  + (size_t)bb * N_SEQ * A_DIM;
  const u16* Kl_g = Kl  + (size_t)bb * N_SEQ * A_DIM;
  const u16* Vh_g = Vth + (size_t)bb * A_DIM * N_SEQ;
  const u16* Vl_g = Vtl + (size_t)bb * A_DIM * N_SEQ;

  // preload this wave's Q fragments (16 queries x 256 dims, hi+lo)
  s16x8 qfh[8], qfl[8];
  {
    const size_t qrow = (size_t)(bb * N_SEQ + q0 + wv * 16 + lm) * A_DIM;
#pragma unroll
    for (int s = 0; s < 8; ++s) {
      qfh[s] = *(const s16x8*)(Qh + qrow + s * 32 + lg * 8);
      qfl[s] = *(const s16x8*)(Ql + qrow + s * 32 + lg * 8);
    }
  }

  f32x4 acc[16] = {};
  float m_run[4] = {-1e30f, -1e30f, -1e30f, -1e30f};
  float l_run[4] = {0.f, 0.f, 0.f, 0.f};

  u16* PW = PL + wv * (16 * 40);

  for (int kt = 0; kt < N_SEQ / KB; ++kt) {
    const int key0 = kt * KB;
    __syncthreads();
    { // stage K hi/lo: row r has 32 16B-slots, swizzle slot ^= (r&7)
      const int r = t >> 3, j = t & 7;
#pragma unroll
      for (int u = 0; u < 4; ++u) {
        const int slot = j * 4 + u;
        const int sw   = slot ^ (r & 7);
        *(s16x8*)(KhL + r * 256 + sw * 8) =
            *(const s16x8*)(Kh_g + (size_t)(key0 + r) * A_DIM + slot * 8);
        *(s16x8*)(KlL + r * 256 + sw * 8) =
            *(const s16x8*)(Kl_g + (size_t)(key0 + r) * A_DIM + slot * 8);
      }
    }
    { // stage V^T hi/lo: row a has 4 16B-slots, swizzle slot ^= (a&3)
      const int a = t;
#pragma unroll
      for (int u = 0; u < 4; ++u) {
        const int sw = u ^ (a & 3);
        *(s16x8*)(VhL + a * 32 + sw * 8) =
            *(const s16x8*)(Vh_g + (size_t)a * N_SEQ + key0 + u * 8);
        *(s16x8*)(VlL + a * 32 + sw * 8) =
            *(const s16x8*)(Vl_g + (size_t)a * N_SEQ + key0 + u * 8);
      }
    }
    __syncthreads();

    // ---- scores: S[16q x 32k] = Q K^T via split-bf16 (hh + hl + lh) ----
    f32x4 S0 = {}, S1 = {};
#pragma unroll
    for (int s = 0; s < 8; ++s) {
      {
        const int kr = lm;
        const int sw = (s * 4 + lg) ^ (kr & 7);
        s16x8 kh = *(const s16x8*)(KhL + kr * 256 + sw * 8);
        s16x8 kl = *(const s16x8*)(KlL + kr * 256 + sw * 8);
        S0 = MFMA(qfh[s], kh, S0);
        S0 = MFMA(qfh[s], kl, S0);
        S0 = MFMA(qfl[s], kh, S0);
      }
      {
        const int kr = 16 + lm;
        const int sw = (s * 4 + lg) ^ (kr & 7);
        s16x8 kh = *(const s16x8*)(KhL + kr * 256 + sw * 8);
        s16x8 kl = *(const s16x8*)(KlL + kr * 256 + sw * 8);
        S1 = MFMA(qfh[s], kh, S1);
        S1 = MFMA(qfh[s], kl, S1);
        S1 = MFMA(qfl[s], kh, S1);
      }
    }

    // ---- online softmax (reg r <-> query lg*4+r; 16-lane butterfly over k)
    float p0[4], p1[4], sc[4];
#pragma unroll
    for (int r = 0; r < 4; ++r) {
      float mx = fmaxf(S0[r], S1[r]);
#pragma unroll
      for (int d = 1; d <= 8; d <<= 1) mx = fmaxf(mx, __shfl_xor(mx, d));
      float mn = fmaxf(m_run[r], mx);
      sc[r] = __expf(m_run[r] - mn);
      p0[r] = __expf(S0[r] - mn);
      p1[r] = __expf(S1[r] - mn);
      float rs = p0[r] + p1[r];
#pragma unroll
      for (int d = 1; d <= 8; d <<= 1) rs += __shfl_xor(rs, d);
      l_run[r] = l_run[r] * sc[r] + rs;
      m_run[r] = mn;
    }
#pragma unroll
    for (int tt = 0; tt < 16; ++tt)
#pragma unroll
      for (int r = 0; r < 4; ++r) acc[tt][r] *= sc[r];

    // ---- P -> LDS (per-wave buffer, transpose to A-frag layout) ----
#pragma unroll
    for (int r = 0; r < 4; ++r) {
      const int q = lg * 4 + r;
      PW[q * 40 + lm]      = f2bf(p0[r]);
      PW[q * 40 + 16 + lm] = f2bf(p1[r]);
    }
    s16x8 pa = *(const s16x8*)(PW + lm * 40 + lg * 8);

    // ---- PV: acc += P (Vh + Vl) ----
#pragma unroll
    for (int tt = 0; tt < 16; ++tt) {
      const int a  = tt * 16 + lm;
      const int sw = lg ^ (a & 3);
      s16x8 vh = *(const s16x8*)(VhL + a * 32 + sw * 8);
      s16x8 vl = *(const s16x8*)(VlL + a * 32 + sw * 8);
      acc[tt] = MFMA(pa, vh, acc[tt]);
      acc[tt] = MFMA(pa, vl, acc[tt]);
    }
  }

  // ---- epilogue: ctx = acc/l, sum over this wave's 16 queries, atomic ----
#pragma unroll
  for (int tt = 0; tt < 16; ++tt) {
    float v = 0.f;
#pragma unroll
    for (int r = 0; r < 4; ++r) v += acc[tt][r] / l_run[r];
    v += __shfl_xor(v, 16);
    v += __shfl_xor(v, 32);
    if (ln < 16) atomicAdd(&out[bb * A_DIM + tt * 16 + ln], v);
  }
}

// ---------------------------------------------------------------------------
extern "C" void kernel_launch(void* const* d_in, const int* in_sizes, int n_in,
                              void* d_out, int out_size, void* d_ws, size_t ws_size,
                              hipStream_t stream) {
  const float* x  = (const float*)d_in[0];
  const float* W1 = (const float*)d_in[1];
  const float* b1 = (const float*)d_in[2];
  const float* W2 = (const float*)d_in[3];
  const float* b2 = (const float*)d_in[4];
  const float* W3 = (const float*)d_in[5];
  const float* b3 = (const float*)d_in[6];
  float* out = (float*)d_out;

  const size_t S1 = (size_t)M_TOT * A_DIM;   // elements per split array
  u16* Qh  = (u16*)d_ws;
  u16* Ql  = Qh + S1;
  u16* Kh  = Ql + S1;
  u16* Kl  = Kh + S1;
  u16* Vth = Kl + S1;
  u16* Vtl = Vth + S1;

  hipMemsetAsync(d_out, 0, (size_t)out_size * sizeof(float), stream);

  proj_kernel<<<dim3((M_TOT / 64) * 12), dim3(256), 0, stream>>>(
      x, W1, b1, W2, b2, W3, b3, Qh, Ql, Kh, Kl, Vth, Vtl);

  const int LDS_BYTES = (32768 + 4 * 16 * 40) * 2;   // 70656
  hipFuncSetAttribute((const void*)attn_kernel,
                      hipFuncAttributeMaxDynamicSharedMemorySize, LDS_BYTES);
  attn_kernel<<<dim3(B_DIM * (N_SEQ / QB)), dim3(256), LDS_BYTES, stream>>>(
      Qh, Ql, Kh, Kl, Vth, Vtl, out);
}

// Round 3
// 344.910 us; speedup vs baseline: 1.9671x; 1.9671x over previous
//
#include <hip/hip_runtime.h>
#include <hip/hip_bf16.h>
#include <stdint.h>

typedef unsigned short u16;
typedef __attribute__((ext_vector_type(8)))  short   s16x8;
typedef __attribute__((ext_vector_type(8)))  __bf16  bf16x8;
typedef __attribute__((ext_vector_type(16))) float   f32x16;

#define B_DIM 16
#define N_SEQ 2048
#define D_DIM 256
#define M_TOT (B_DIM * N_SEQ)   // 32768

static __device__ __forceinline__ u16 f2bf(float f) {
  union { float f; uint32_t u; } v; v.f = f;
  uint32_t u = v.u;
  return (u16)((u + 0x7FFFu + ((u >> 16) & 1u)) >> 16);   // RNE
}
static __device__ __forceinline__ float bf2f(u16 h) {
  union { uint32_t u; float f; } v; v.u = ((uint32_t)h) << 16;
  return v.f;
}

static __device__ __forceinline__ f32x16 MFMA32(s16x8 a, s16x8 b, f32x16 c) {
  return __builtin_amdgcn_mfma_f32_32x32x16_bf16(
      __builtin_bit_cast(bf16x8, a), __builtin_bit_cast(bf16x8, b), c, 0, 0, 0);
}

// load 16 reg fragments (one 256-deep row, hi or lo) for lane half g
static __device__ __forceinline__ void load_frags(const u16* base, s16x8* f, int g) {
#pragma unroll
  for (int c = 0; c < 16; ++c) f[c] = *(const s16x8*)(base + c * 16 + g * 8);
}

// Stage 32 rows x 256 u16 (hi then lo) into LDS buffer with involution swizzle:
// global (row, slot) lives at LDS (row, slot ^ (row&7)); gload_lds dest is linear,
// so the SOURCE address carries the swizzle (rule #21).
static __device__ __forceinline__ void stage_bf16(
    const u16* __restrict__ srcH, const u16* __restrict__ srcL,
    char* lds, int row0, int t)
{
  const int rsub = t >> 5;                  // 0..7
  const int s2   = (t & 31) ^ rsub;         // swizzled 16B-slot (rsub&7 == rsub)
  const size_t so = ((size_t)row0 + rsub) * 512 + (size_t)s2 * 16;  // bytes
  const char* gh = (const char*)srcH + so;
  const char* gl = (const char*)srcL + so;
  char* lh = lds + t * 16;
  char* ll = lds + 16384 + t * 16;
#pragma unroll
  for (int j = 0; j < 4; ++j)
    __builtin_amdgcn_global_load_lds(
        (const __attribute__((address_space(1))) uint32_t*)(gh + j * 4096),
        (__attribute__((address_space(3))) uint32_t*)(lh + j * 4096), 16, 0, 0);
#pragma unroll
  for (int j = 0; j < 4; ++j)
    __builtin_amdgcn_global_load_lds(
        (const __attribute__((address_space(1))) uint32_t*)(gl + j * 4096),
        (__attribute__((address_space(3))) uint32_t*)(ll + j * 4096), 16, 0, 0);
}

// ---------------------------------------------------------------------------
// W split+transpose: WT[a][k] (a<256: W1, else W2), bf16 hi/lo
// ---------------------------------------------------------------------------
__global__ void splitW_kernel(const float* __restrict__ W1, const float* __restrict__ W2,
                              u16* __restrict__ WTh, u16* __restrict__ WTl) {
  const int gid = blockIdx.x * 256 + threadIdx.x;   // 512 blocks -> 131072
  const int a = gid >> 8, k = gid & 255;
  const float v = (a < 256) ? W1[k * 256 + a] : W2[k * 256 + (a - 256)];
  const u16 h = f2bf(v);
  WTh[gid] = h;
  WTl[gid] = f2bf(v - bf2f(h));
}

// ---------------------------------------------------------------------------
// Projection: [Q|K][m][a] = x@[W1|W2]+bias, split-bf16 out.
// W (32 a-cols/wave) in regs; x streamed 32 rows/iter, reg-staged f32->bf16
// hi/lo into swizzled LDS. grid = 4 a-blocks x 128 m-chunks.
// ---------------------------------------------------------------------------
__global__ __launch_bounds__(256, 2) void proj_kernel(
    const float* __restrict__ x,
    const u16* __restrict__ WTh, const u16* __restrict__ WTl,
    const float* __restrict__ b1, const float* __restrict__ b2,
    u16* __restrict__ Qh, u16* __restrict__ Ql,
    u16* __restrict__ Kh, u16* __restrict__ Kl)
{
  extern __shared__ char lds[];   // 2 x (16KB hi + 16KB lo)
  const int t = threadIdx.x, wv = t >> 6, ln = t & 63, lr = ln & 31, g = ln >> 5;
  const int ablk = blockIdx.x & 3;
  const int m0 = (blockIdx.x >> 2) * 256;
  const int aglob = ablk * 128 + wv * 32 + lr;

  s16x8 wfh[16], wfl[16];
  load_frags(WTh + (size_t)aglob * 256, wfh, g);
  load_frags(WTl + (size_t)aglob * 256, wfl, g);
  const float bias = (aglob < 256) ? b1[aglob] : b2[aglob - 256];
  u16* Oh = (ablk < 2) ? Qh : Kh;
  u16* Ol = (ablk < 2) ? Ql : Kl;
  const int acol = aglob & 255;

  const int srow = t >> 3;            // staging: row 0..31
  const int scol = (t & 7) * 32;      // 32 f32 per thread

  float4 v[8];
  // prologue: load rows m0, convert, write buf0
  {
    const float* src = x + (size_t)(m0 + srow) * 256 + scol;
#pragma unroll
    for (int j = 0; j < 8; ++j) v[j] = *(const float4*)(src + j * 4);
#pragma unroll
    for (int q8 = 0; q8 < 4; ++q8) {
      float ff[8] = {v[q8*2].x, v[q8*2].y, v[q8*2].z, v[q8*2].w,
                     v[q8*2+1].x, v[q8*2+1].y, v[q8*2+1].z, v[q8*2+1].w};
      s16x8 H, L;
#pragma unroll
      for (int e = 0; e < 8; ++e) {
        u16 h = f2bf(ff[e]); H[e] = (short)h; L[e] = (short)f2bf(ff[e] - bf2f(h));
      }
      const int swz = (((t & 7) * 4 + q8) ^ (srow & 7));
      *(s16x8*)(lds + srow * 512 + swz * 16) = H;
      *(s16x8*)(lds + 16384 + srow * 512 + swz * 16) = L;
    }
  }
  __syncthreads();
  int p = 0;
  for (int it = 0; it < 8; ++it) {
    if (it + 1 < 8) {   // issue next-tile global loads early (overlap MFMA)
      const float* src = x + (size_t)(m0 + (it + 1) * 32 + srow) * 256 + scol;
#pragma unroll
      for (int j = 0; j < 8; ++j) v[j] = *(const float4*)(src + j * 4);
    }
    const char* bh = lds + p * 32768;
    const char* bl = bh + 16384;
    f32x16 S = {};
#pragma unroll
    for (int cc = 0; cc < 16; ++cc) {
      const int sl = ((cc * 2 + g) ^ (lr & 7)) * 16;
      s16x8 ah = *(const s16x8*)(bh + lr * 512 + sl);
      s16x8 al = *(const s16x8*)(bl + lr * 512 + sl);
      S = MFMA32(ah, wfh[cc], S);
      S = MFMA32(ah, wfl[cc], S);
      S = MFMA32(al, wfh[cc], S);
    }
    // write outputs: 32 m-rows x wave's 32 a-cols (coalesced 64B rows)
#pragma unroll
    for (int i = 0; i < 16; ++i) {
      const int mrow = m0 + it * 32 + (i & 3) + 8 * (i >> 2) + 4 * g;
      const float val = S[i] + bias;
      const u16 h = f2bf(val);
      const u16 lo2 = f2bf(val - bf2f(h));
      const size_t idx = (size_t)mrow * 256 + acol;
      Oh[idx] = h; Ol[idx] = lo2;
    }
    if (it + 1 < 8) {   // convert + write next tile into other buffer
      char* basep = lds + (p ^ 1) * 32768;
#pragma unroll
      for (int q8 = 0; q8 < 4; ++q8) {
        float ff[8] = {v[q8*2].x, v[q8*2].y, v[q8*2].z, v[q8*2].w,
                       v[q8*2+1].x, v[q8*2+1].y, v[q8*2+1].z, v[q8*2+1].w};
        s16x8 H, L;
#pragma unroll
        for (int e = 0; e < 8; ++e) {
          u16 h = f2bf(ff[e]); H[e] = (short)h; L[e] = (short)f2bf(ff[e] - bf2f(h));
        }
        const int swz = (((t & 7) * 4 + q8) ^ (srow & 7));
        *(s16x8*)(basep + srow * 512 + swz * 16) = H;
        *(s16x8*)(basep + 16384 + srow * 512 + swz * 16) = L;
      }
    }
    __syncthreads();
    p ^= 1;
  }
}

// ---------------------------------------------------------------------------
// Pass 1: per-query (m, l) over one k-half. A = K (LDS), B = Q (regs).
// S^T[key][q]: lane holds 16 keys x 1 query -> lane-local softmax reduce.
// ---------------------------------------------------------------------------
__global__ __launch_bounds__(256, 2) void pass1_kernel(
    const u16* __restrict__ Qh, const u16* __restrict__ Ql,
    const u16* __restrict__ Kh, const u16* __restrict__ Kl,
    float* __restrict__ mpart, float* __restrict__ lpart)
{
  extern __shared__ char lds[];
  const int t = threadIdx.x, wv = t >> 6, ln = t & 63, lr = ln & 31, g = ln >> 5;
  const int qblk = blockIdx.x >> 1;
  const int khalf = blockIdx.x & 1;
  const int b = qblk >> 4;
  const int q0b = (qblk & 15) * 128;
  const int qrow = b * 2048 + q0b + wv * 32 + lr;

  s16x8 qfh[16], qfl[16];
  load_frags(Qh + (size_t)qrow * 256, qfh, g);
  load_frags(Ql + (size_t)qrow * 256, qfl, g);

  const int krow0 = b * 2048 + khalf * 1024;
  float m_run = -1e30f, l_run = 0.f;

  stage_bf16(Kh, Kl, lds, krow0, t);
  __syncthreads();
  int p = 0;
  for (int it = 0; it < 32; ++it) {
    if (it + 1 < 32) stage_bf16(Kh, Kl, lds + (p ^ 1) * 32768, krow0 + (it + 1) * 32, t);
    const char* bh = lds + p * 32768;
    const char* bl = bh + 16384;
    f32x16 S = {};
#pragma unroll
    for (int cc = 0; cc < 16; ++cc) {
      const int sl = ((cc * 2 + g) ^ (lr & 7)) * 16;
      s16x8 ah = *(const s16x8*)(bh + lr * 512 + sl);
      s16x8 al = *(const s16x8*)(bl + lr * 512 + sl);
      S = MFMA32(ah, qfh[cc], S);   // Kh*Qh
      S = MFMA32(ah, qfl[cc], S);   // Kh*Ql
      S = MFMA32(al, qfh[cc], S);   // Kl*Qh
    }
    float mx = S[0];
#pragma unroll
    for (int i = 1; i < 16; ++i) mx = fmaxf(mx, S[i]);
    mx = fmaxf(mx, __shfl_xor(mx, 32));
    const float mn = fmaxf(m_run, mx);
    float rs = 0.f;
#pragma unroll
    for (int i = 0; i < 16; ++i) rs += __expf(S[i] - mn);
    rs += __shfl_xor(rs, 32);
    l_run = l_run * __expf(m_run - mn) + rs;
    m_run = mn;
    __syncthreads();
    p ^= 1;
  }
  if (ln < 32) {
    const int q = b * 2048 + q0b + wv * 32 + ln;
    mpart[khalf * M_TOT + q] = m_run;
    lpart[khalf * M_TOT + q] = l_run;
  }
}

__global__ void merge_kernel(const float* __restrict__ mpart, const float* __restrict__ lpart,
                             float* __restrict__ mfin, float* __restrict__ linv) {
  const int q = blockIdx.x * 256 + threadIdx.x;
  const float m0 = mpart[q], m1 = mpart[M_TOT + q];
  const float l0 = lpart[q], l1 = lpart[M_TOT + q];
  const float m = fmaxf(m0, m1);
  const float l = l0 * __expf(m0 - m) + l1 * __expf(m1 - m);
  mfin[q] = m;
  linv[q] = 1.f / l;
}

// ---------------------------------------------------------------------------
// Pass 2: c_k = sum_q exp(S-m_q)*invl_q. A = K (regs), B = Q (LDS).
// Identical MFMA inputs+order as pass1 -> bitwise-identical S -> consistent w.
// ---------------------------------------------------------------------------
__global__ __launch_bounds__(256, 2) void pass2_kernel(
    const u16* __restrict__ Qh, const u16* __restrict__ Ql,
    const u16* __restrict__ Kh, const u16* __restrict__ Kl,
    const float* __restrict__ mfin, const float* __restrict__ linv,
    float* __restrict__ cvec)
{
  extern __shared__ char lds[];
  const int t = threadIdx.x, wv = t >> 6, ln = t & 63, lr = ln & 31, g = ln >> 5;
  const int kblk = blockIdx.x >> 1;
  const int qhalf = blockIdx.x & 1;
  const int b = kblk >> 4;
  const int k0b = (kblk & 15) * 128;
  const int krow = b * 2048 + k0b + wv * 32 + lr;

  s16x8 kfh[16], kfl[16];
  load_frags(Kh + (size_t)krow * 256, kfh, g);
  load_frags(Kl + (size_t)krow * 256, kfl, g);

  const int qrow0 = b * 2048 + qhalf * 1024;
  float ck[16];
#pragma unroll
  for (int i = 0; i < 16; ++i) ck[i] = 0.f;

  stage_bf16(Qh, Ql, lds, qrow0, t);
  __syncthreads();
  int p = 0;
  for (int it = 0; it < 32; ++it) {
    if (it + 1 < 32) stage_bf16(Qh, Ql, lds + (p ^ 1) * 32768, qrow0 + (it + 1) * 32, t);
    const float mq = mfin[qrow0 + it * 32 + lr];
    const float il = linv[qrow0 + it * 32 + lr];
    const char* bh = lds + p * 32768;
    const char* bl = bh + 16384;
    f32x16 S = {};
#pragma unroll
    for (int cc = 0; cc < 16; ++cc) {
      const int sl = ((cc * 2 + g) ^ (lr & 7)) * 16;
      s16x8 qh_ = *(const s16x8*)(bh + lr * 512 + sl);
      s16x8 ql_ = *(const s16x8*)(bl + lr * 512 + sl);
      S = MFMA32(kfh[cc], qh_, S);   // Kh*Qh
      S = MFMA32(kfh[cc], ql_, S);   // Kh*Ql
      S = MFMA32(kfl[cc], qh_, S);   // Kl*Qh
    }
#pragma unroll
    for (int i = 0; i < 16; ++i) ck[i] += __expf(S[i] - mq) * il;
    __syncthreads();
    p ^= 1;
  }
  // reduce over the 32 q-columns (lanes within each half)
#pragma unroll
  for (int i = 0; i < 16; ++i) {
#pragma unroll
    for (int d = 1; d <= 16; d <<= 1) ck[i] += __shfl_xor(ck[i], d);
  }
  if (lr == 0) {
#pragma unroll
    for (int i = 0; i < 16; ++i) {
      const int klocal = (i & 3) + 8 * (i >> 2) + 4 * g;
      atomicAdd(&cvec[b * 2048 + k0b + wv * 32 + klocal], ck[i]);
    }
  }
}

// y[b][d] = sum_k c_k x[b,k,d]; sumc[b] = sum_k c_k
__global__ void reducey_kernel(const float* __restrict__ x, const float* __restrict__ cvec,
                               float* __restrict__ yv, float* __restrict__ sumc) {
  const int b = blockIdx.x >> 4, kc = blockIdx.x & 15, tid = threadIdx.x;
  const float* xb = x + ((size_t)b * 2048 + kc * 128) * 256;
  const float* cb = cvec + b * 2048 + kc * 128;
  float acc = 0.f;
  for (int k = 0; k < 128; ++k) acc = fmaf(cb[k], xb[(size_t)k * 256 + tid], acc);
  atomicAdd(&yv[b * 256 + tid], acc);
  if (tid == 0) {
    float s = 0.f;
    for (int k = 0; k < 128; ++k) s += cb[k];
    atomicAdd(&sumc[b], s);
  }
}

// out[b][a] = sum_d y[b,d] W3[d,a] + sumc[b]*b3[a]
__global__ void final_kernel(const float* __restrict__ yv, const float* __restrict__ sumc,
                             const float* __restrict__ W3, const float* __restrict__ b3,
                             float* __restrict__ out) {
  __shared__ float ys[256];
  const int b = blockIdx.x, a = threadIdx.x;
  ys[a] = yv[b * 256 + a];
  __syncthreads();
  float acc = sumc[b] * b3[a];
#pragma unroll 4
  for (int d = 0; d < 256; ++d) acc = fmaf(ys[d], W3[d * 256 + a], acc);
  out[b * 256 + a] = acc;
}

// ---------------------------------------------------------------------------
extern "C" void kernel_launch(void* const* d_in, const int* in_sizes, int n_in,
                              void* d_out, int out_size, void* d_ws, size_t ws_size,
                              hipStream_t stream) {
  const float* x  = (const float*)d_in[0];
  const float* W1 = (const float*)d_in[1];
  const float* b1 = (const float*)d_in[2];
  const float* W2 = (const float*)d_in[3];
  const float* b2 = (const float*)d_in[4];
  const float* W3 = (const float*)d_in[5];
  const float* b3 = (const float*)d_in[6];
  float* out = (float*)d_out;

  char* ws = (char*)d_ws;
  const size_t SZ_WT = 512u * 256u * 2u;          // 262144
  const size_t SZ_QK = (size_t)M_TOT * 256u * 2u; // 16777216
  u16* WTh = (u16*)(ws);                 ws += SZ_WT;
  u16* WTl = (u16*)(ws);                 ws += SZ_WT;
  u16* Qh  = (u16*)(ws);                 ws += SZ_QK;
  u16* Ql  = (u16*)(ws);                 ws += SZ_QK;
  u16* Kh  = (u16*)(ws);                 ws += SZ_QK;
  u16* Kl  = (u16*)(ws);                 ws += SZ_QK;
  float* mpart = (float*)(ws);           ws += 2u * M_TOT * 4u;
  float* lpart = (float*)(ws);           ws += 2u * M_TOT * 4u;
  float* mfin  = (float*)(ws);           ws += (size_t)M_TOT * 4u;
  float* linv  = (float*)(ws);           ws += (size_t)M_TOT * 4u;
  float* cvec  = (float*)(ws);           ws += (size_t)M_TOT * 4u;
  float* yv    = (float*)(ws);           ws += 4096u * 4u;
  float* sumc  = (float*)(ws);           ws += 64u;

  hipMemsetAsync(cvec, 0, (size_t)M_TOT * 4u + 4096u * 4u + 64u, stream);

  const int LDSB = 65536;
  hipFuncSetAttribute((const void*)proj_kernel,  hipFuncAttributeMaxDynamicSharedMemorySize, LDSB);
  hipFuncSetAttribute((const void*)pass1_kernel, hipFuncAttributeMaxDynamicSharedMemorySize, LDSB);
  hipFuncSetAttribute((const void*)pass2_kernel, hipFuncAttributeMaxDynamicSharedMemorySize, LDSB);

  splitW_kernel<<<dim3(512), dim3(256), 0, stream>>>(W1, W2, WTh, WTl);
  proj_kernel<<<dim3(512), dim3(256), LDSB, stream>>>(x, WTh, WTl, b1, b2, Qh, Ql, Kh, Kl);
  pass1_kernel<<<dim3(512), dim3(256), LDSB, stream>>>(Qh, Ql, Kh, Kl, mpart, lpart);
  merge_kernel<<<dim3(128), dim3(256), 0, stream>>>(mpart, lpart, mfin, linv);
  pass2_kernel<<<dim3(512), dim3(256), LDSB, stream>>>(Qh, Ql, Kh, Kl, mfin, linv, cvec);
  reducey_kernel<<<dim3(256), dim3(256), 0, stream>>>(x, cvec, yv, sumc);
  final_kernel<<<dim3(16), dim3(256), 0, stream>>>(yv, sumc, W3, b3, out);
}